// Round 5
// baseline (462.938 us; speedup 1.0000x reference)
//
#include <hip/hip_runtime.h>
#include <math.h>

#define NB 2
#define SEQL 4096
#define NH 16
#define HD 128
#define HDV 128
#define CHK 1024
#define BQ 128
#define BK 64
#define KSTR 136       // 128 + 8 pad (u16 units)
#define VSTR 72        // 64 + 8 pad (u16 units)
#define OUTW 2048      // NH*HDV
#define NEGB (-1e30f)
#define L2B64 0.20762050593045702f  // log2(10000)/64

typedef _Float16 f16x8 __attribute__((ext_vector_type(8)));
typedef float f32x4 __attribute__((ext_vector_type(4)));
typedef unsigned short u16x8 __attribute__((ext_vector_type(8)));

static __device__ __forceinline__ unsigned short f2h(float f) {
  return __builtin_bit_cast(unsigned short, (_Float16)f);
}
static __device__ __forceinline__ f16x8 ld8(const unsigned short* p) {
  return __builtin_bit_cast(f16x8, *(const u16x8*)p);
}
// Range-reduced fast sincos: v_sin/v_cos need reduced args (ISA: reduce via fract).
static __device__ __forceinline__ void fast_sincos(float t, float* sn, float* cs) {
  const float INV2PI = 0.15915494309189535f;
  const float TWOPI  = 6.283185307179586f;
  float rev = t * INV2PI;
  rev -= floorf(rev);
  float ang = rev * TWOPI;
  *sn = __sinf(ang);
  *cs = __cosf(ang);
}

__global__ __launch_bounds__(256) void megalodon_attn_k(
    const float* __restrict__ q,
    const float* __restrict__ k,
    const float* __restrict__ v,
    float* __restrict__ out,
    const int* __restrict__ startp) {

  // LDS: sK (64x136), sVT (128x72), sP (4 waves x 32x72). f16 storage.
  __shared__ __align__(16) unsigned short smem[27136]; // 54272 B
  unsigned short* sK  = smem;            // 8704 u16
  unsigned short* sVT = smem + 8704;     // 9216 u16
  unsigned short* sP  = smem + 17920;    // 9216 u16

  const int tid  = threadIdx.x;
  const int lane = tid & 63;
  const int wv   = tid >> 6;
  const int ln15 = lane & 15;
  const int quad = lane >> 4;

  const int bid = blockIdx.x;
  const int qt  = bid & 7;
  const int h   = (bid >> 3) & 15;
  const int n   = (bid >> 7) & 3;
  const int b   = bid >> 9;

  const int s0 = startp[0];
  const float scale = 0.08838834764831845f; // 1/sqrt(128)
  const int l0 = n * CHK + qt * BQ;         // first Q row (global l)

  // ---- Q fragments direct from global (fp32), RoPE in registers (scale folded) ----
  // A-operand layout: m = lane&15, k = quad*8 + j; qf[rt][kf] covers k = kf*32+quad*8..+7
  f16x8 qf[2][4];
#pragma unroll
  for (int rt = 0; rt < 2; ++rt) {
    const int l = l0 + wv * 32 + rt * 16 + ln15;
    const float* qp = q + ((size_t)(b * SEQL + l) * NH + h) * HD;
#pragma unroll
    for (int kf2 = 0; kf2 < 2; ++kf2) {
      const int c0 = kf2 * 32 + quad * 8;
      float xa[8], xb[8];
      *(f32x4*)&xa[0] = *(const f32x4*)(qp + c0);
      *(f32x4*)&xa[4] = *(const f32x4*)(qp + c0 + 4);
      *(f32x4*)&xb[0] = *(const f32x4*)(qp + c0 + 64);
      *(f32x4*)&xb[4] = *(const f32x4*)(qp + c0 + 68);
      f16x8 lo, hi;
#pragma unroll
      for (int j = 0; j < 8; ++j) {
        const int dd = c0 + j;
        float x1 = xa[j];
        float x2 = xb[j];
        float freq = exp2f(-L2B64 * (float)dd);
        float t = (float)(l + s0) * freq;
        float sn, cs;
        fast_sincos(t, &sn, &cs);
        lo[j] = (_Float16)((x1 * cs - x2 * sn) * scale);
        hi[j] = (_Float16)((x2 * cs + x1 * sn) * scale);
      }
      qf[rt][kf2]     = lo;
      qf[rt][kf2 + 2] = hi;
    }
  }

  f32x4 oacc[2][8];
  float m_run[2][4], l_run[2][4];
#pragma unroll
  for (int rt = 0; rt < 2; ++rt) {
#pragma unroll
    for (int vt = 0; vt < 8; ++vt) { f32x4 z = {0.f, 0.f, 0.f, 0.f}; oacc[rt][vt] = z; }
#pragma unroll
    for (int rg = 0; rg < 4; ++rg) { m_run[rt][rg] = NEGB; l_run[rt][rg] = 0.f; }
  }

  // per-thread loop-invariant RoPE freq for K staging (dd = tid&63 in that loop)
  const float kfreq = exp2f(-L2B64 * (float)(tid & 63));

  const int ntiles = 2 * qt + 2;
  for (int j = 0; j < ntiles; ++j) {
    __syncthreads(); // previous tile's LDS reads done before restaging
    const int kl0 = n * CHK + j * BK;

    // stage K tile with RoPE (fp32 reads, f16 LDS)
    for (int idx = tid; idx < BK * 64; idx += 256) {
      int r = idx >> 6, dd = idx & 63; // dd == tid&63 (stride 256)
      int l = kl0 + r;
      const float* kp = k + ((size_t)(b * SEQL + l) * NH + h) * HD;
      float x1 = kp[dd];
      float x2 = kp[dd + 64];
      float t = (float)(l + s0) * kfreq;
      float sn, cs;
      fast_sincos(t, &sn, &cs);
      sK[r * KSTR + dd]      = f2h(x1 * cs - x2 * sn);
      sK[r * KSTR + dd + 64] = f2h(x2 * cs + x1 * sn);
    }
    // stage V transposed: sVT[vcol][kk]; coalesced fp32 reads, b128 LDS writes
    for (int idx = tid; idx < HDV * (BK / 8); idx += 256) {
      int vc = idx & 127;
      int sk = idx >> 7;
      u16x8 vv;
#pragma unroll
      for (int i = 0; i < 8; ++i)
        vv[i] = f2h(v[((size_t)(b * SEQL + kl0 + sk * 8 + i) * NH + h) * HDV + vc]);
      *(u16x8*)&sVT[vc * VSTR + sk * 8] = vv;
    }
    __syncthreads();

    // waves entirely above this K-tile's diagonal: whole tile masked -> skip compute
    if (j * BK <= qt * BQ + wv * 32 + 31) {
      // ---- S = Q K^T (per wave: 32 rows x 64 cols) ----
      f32x4 sacc[2][4];
#pragma unroll
      for (int rt = 0; rt < 2; ++rt)
#pragma unroll
        for (int ct = 0; ct < 4; ++ct) { f32x4 z = {0.f, 0.f, 0.f, 0.f}; sacc[rt][ct] = z; }
#pragma unroll
      for (int ct = 0; ct < 4; ++ct) {
#pragma unroll
        for (int kf = 0; kf < 4; ++kf) {
          f16x8 kb = ld8(&sK[(ct * 16 + ln15) * KSTR + kf * 32 + quad * 8]);
          sacc[0][ct] = __builtin_amdgcn_mfma_f32_16x16x32_f16(qf[0][kf], kb, sacc[0][ct], 0, 0, 0);
          sacc[1][ct] = __builtin_amdgcn_mfma_f32_16x16x32_f16(qf[1][kf], kb, sacc[1][ct], 0, 0, 0);
        }
      }

      // ---- online softmax; C/D layout: row = quad*4+reg, col = ct*16 + ln15 ----
      // All-finite arithmetic: sentinel -1e30, exp args always finite.
      const int colb = j * BK + ln15;
      float alpha[2][4];
#pragma unroll
      for (int rt = 0; rt < 2; ++rt) {
        const int rowq = qt * BQ + wv * 32 + rt * 16 + quad * 4;
#pragma unroll
        for (int rg = 0; rg < 4; ++rg) {
          const int row = rowq + rg;
          float mx = NEGB;
#pragma unroll
          for (int ct = 0; ct < 4; ++ct) {
            float sv = sacc[rt][ct][rg];
            sv = (colb + ct * 16 <= row) ? sv : NEGB;
            sacc[rt][ct][rg] = sv;
            mx = fmaxf(mx, sv);
          }
          mx = fmaxf(mx, __shfl_xor(mx, 1));
          mx = fmaxf(mx, __shfl_xor(mx, 2));
          mx = fmaxf(mx, __shfl_xor(mx, 4));
          mx = fmaxf(mx, __shfl_xor(mx, 8));
          float mo = m_run[rt][rg];
          float mn = fmaxf(mo, mx);
          m_run[rt][rg] = mn;
          float al = __expf(mo - mn); // mo=-1e30 first tile -> 0
          alpha[rt][rg] = al;
          float rs = 0.f;
#pragma unroll
          for (int ct = 0; ct < 4; ++ct) {
            float p = __expf(sacc[rt][ct][rg] - mn); // masked: exp(-1e30 - mn) = 0
            rs += p;
            sP[wv * (32 * VSTR) + (rt * 16 + quad * 4 + rg) * VSTR + ct * 16 + ln15] = f2h(p);
          }
          rs += __shfl_xor(rs, 1);
          rs += __shfl_xor(rs, 2);
          rs += __shfl_xor(rs, 4);
          rs += __shfl_xor(rs, 8);
          l_run[rt][rg] = l_run[rt][rg] * al + rs;
        }
      }
#pragma unroll
      for (int rt = 0; rt < 2; ++rt)
#pragma unroll
        for (int vt = 0; vt < 8; ++vt)
#pragma unroll
          for (int rg = 0; rg < 4; ++rg) oacc[rt][vt][rg] *= alpha[rt][rg];

      // per-wave P buffer: same-wave DS ops are in order; drain returns before reads
      asm volatile("s_waitcnt lgkmcnt(0)" ::: "memory");

      // ---- O += P V ----
#pragma unroll
      for (int kf = 0; kf < 2; ++kf) {
        f16x8 pa0 = ld8(&sP[wv * (32 * VSTR) + (ln15) * VSTR + kf * 32 + quad * 8]);
        f16x8 pa1 = ld8(&sP[wv * (32 * VSTR) + (16 + ln15) * VSTR + kf * 32 + quad * 8]);
#pragma unroll
        for (int vt = 0; vt < 8; ++vt) {
          f16x8 vb = ld8(&sVT[(vt * 16 + ln15) * VSTR + kf * 32 + quad * 8]);
          oacc[0][vt] = __builtin_amdgcn_mfma_f32_16x16x32_f16(pa0, vb, oacc[0][vt], 0, 0, 0);
          oacc[1][vt] = __builtin_amdgcn_mfma_f32_16x16x32_f16(pa1, vb, oacc[1][vt], 0, 0, 0);
        }
      }
    } // wave skip
  }   // K-tile loop

  // ---- epilogue: normalize, store fp32 ----
#pragma unroll
  for (int rt = 0; rt < 2; ++rt) {
#pragma unroll
    for (int rg = 0; rg < 4; ++rg) {
      const int l = l0 + wv * 32 + rt * 16 + quad * 4 + rg;
      const float lr = l_run[rt][rg];
      const float inv = (lr > 0.f) ? (1.0f / lr) : 0.f;
      float* op = out + (size_t)(b * SEQL + l) * OUTW + h * HDV + ln15;
#pragma unroll
      for (int vt = 0; vt < 8; ++vt)
        op[vt * 16] = oacc[rt][vt][rg] * inv;
    }
  }
}

extern "C" void kernel_launch(void* const* d_in, const int* in_sizes, int n_in,
                              void* d_out, int out_size, void* d_ws, size_t ws_size,
                              hipStream_t stream) {
  const float* q = (const float*)d_in[0];
  const float* k = (const float*)d_in[1];
  const float* v = (const float*)d_in[2];
  const int* start = (const int*)d_in[3];
  (void)d_ws; (void)ws_size; (void)in_sizes; (void)n_in; (void)out_size;

  megalodon_attn_k<<<NB * 4 * NH * 8, 256, 0, stream>>>(
      q, k, v, (float*)d_out, start);
}